// Round 13
// baseline (251.444 us; speedup 1.0000x reference)
//
#include <hip/hip_runtime.h>
#include <math.h>

// ---------------------------------------------------------------------------
// GraphTransformer: GCNConv(64->64)+ReLU -> TransformerConv(h=1) -> GCNConv(64->64)
// N=50000, E=800000, D=64, fp32 in/out.
// Round 13: fused GEMM phases were at 100% LDS bandwidth (9.6 MB/CU of
// ds_read_b128 = 47 us = fusedA's duration). Restructured: 64-row blocks,
// 4x8 (A) / 2x4 (B) thread tiles, W staged TRANSPOSED as bf16 (uint4 = 8k
// per read) -> ~4.5x fewer LDS bytes. Gathers/CSR unchanged.
// ---------------------------------------------------------------------------

#define D 64
#define BKT_SHIFT 9
#define CAP 12288
#define CHUNK 4096

__device__ __forceinline__ unsigned short f2bf(float f) {
    unsigned int u = __float_as_uint(f);
    u += 0x7FFFu + ((u >> 16) & 1u);
    return (unsigned short)(u >> 16);
}
#define BF_LO(u) __uint_as_float((u) << 16)
#define BF_HI(u) __uint_as_float((u) & 0xFFFF0000u)

// ============================ CSR build ====================================

__global__ void init_gcursor(int* __restrict__ gcursor) {
    if (threadIdx.x < 128) gcursor[threadIdx.x] = 0;
}

__global__ __launch_bounds__(256) void binA_kernel(const int* __restrict__ src,
                                                   const int* __restrict__ dst,
                                                   int* __restrict__ gcursor,
                                                   unsigned int* __restrict__ staging,
                                                   int e, int nbkt) {
    __shared__ int cntB[128];
    __shared__ int offB[128];
    __shared__ int curB[128];
    __shared__ int gbase[128];
    __shared__ unsigned int pairs[CHUNK];
    __shared__ unsigned char bkt[CHUNK];

    int t = threadIdx.x;
    int e0 = blockIdx.x * CHUNK;
    int ecnt = min(CHUNK, e - e0);

    if (t < 128) cntB[t] = 0;
    __syncthreads();

    int myS[CHUNK / 256], myD[CHUNK / 256];
    #pragma unroll
    for (int i = 0; i < CHUNK / 256; ++i) {
        int idx = t + 256 * i;
        if (idx < ecnt) {
            myS[i] = src[e0 + idx];
            myD[i] = dst[e0 + idx];
            atomicAdd(&cntB[myD[i] >> BKT_SHIFT], 1);
        }
    }
    __syncthreads();
    if (t < 128) offB[t] = cntB[t];
    __syncthreads();
    for (int off = 1; off < 128; off <<= 1) {
        int add = (t < 128 && t >= off) ? offB[t - off] : 0;
        __syncthreads();
        if (t < 128) offB[t] += add;
        __syncthreads();
    }
    if (t < 128) {
        int excl = offB[t] - cntB[t];
        offB[t] = excl;
        curB[t] = excl;
        if (t < nbkt && cntB[t] > 0) gbase[t] = atomicAdd(&gcursor[t], cntB[t]);
    }
    __syncthreads();
    #pragma unroll
    for (int i = 0; i < CHUNK / 256; ++i) {
        int idx = t + 256 * i;
        if (idx < ecnt) {
            int b = myD[i] >> BKT_SHIFT;
            int p = atomicAdd(&curB[b], 1);
            pairs[p] = ((unsigned int)myD[i] << 16) | (unsigned int)myS[i];
            bkt[p] = (unsigned char)b;
        }
    }
    __syncthreads();
    for (int p = t; p < ecnt; p += 256) {
        int b = bkt[p];
        staging[(size_t)b * CAP + gbase[b] + (p - offB[b])] = pairs[p];
    }
}

__global__ __launch_bounds__(256) void binB_kernel(const int* __restrict__ gcursor,
                                                   const unsigned int* __restrict__ staging,
                                                   unsigned short* __restrict__ esrc,
                                                   int* __restrict__ cnt,
                                                   int* __restrict__ rowptr,
                                                   float* __restrict__ dinv,
                                                   int n, int nbkt) {
    __shared__ int bpre[128];
    __shared__ int c512[512];
    __shared__ int o512[512];
    int t = threadIdx.x;
    int b = blockIdx.x;

    if (t < 128) bpre[t] = (t < nbkt) ? gcursor[t] : 0;
    __syncthreads();
    for (int off = 1; off < 128; off <<= 1) {
        int add = (t < 128 && t >= off) ? bpre[t - off] : 0;
        __syncthreads();
        if (t < 128) bpre[t] += add;
        __syncthreads();
    }
    int base_b = (b == 0) ? 0 : bpre[b - 1];
    int cnt_b = gcursor[b];
    int lo = b << BKT_SHIFT;

    c512[t] = 0; c512[t + 256] = 0;
    __syncthreads();
    const unsigned int* st = staging + (size_t)b * CAP;
    for (int i = t; i < cnt_b; i += 256)
        atomicAdd(&c512[(int)(st[i] >> 16) - lo], 1);
    __syncthreads();
    o512[t] = c512[t]; o512[t + 256] = c512[t + 256];
    __syncthreads();
    for (int off = 1; off < 512; off <<= 1) {
        int a1 = (t >= off) ? o512[t - off] : 0;
        int a2 = o512[t + 256 - off];
        __syncthreads();
        o512[t] += a1; o512[t + 256] += a2;
        __syncthreads();
    }
    int e1 = o512[t] - c512[t];
    int e2 = o512[t + 256] - c512[t + 256];
    __syncthreads();
    o512[t] = e1; o512[t + 256] = e2;
    __syncthreads();
    for (int i = t; i < 512; i += 256) {
        int g = lo + i;
        if (g < n) {
            int c = c512[i];
            cnt[g] = c;
            rowptr[g] = base_b + o512[i];
            dinv[g] = rsqrtf((float)c + 1.0f);
        }
    }
    __syncthreads();
    for (int i = t; i < cnt_b; i += 256) {
        unsigned int pk = st[i];
        int local = (int)(pk >> 16) - lo;
        int p = atomicAdd(&o512[local], 1);
        esrc[base_b + p] = (unsigned short)(pk & 0xFFFFu);
    }
}

// ============ GEMM 64x64, epilogue: bf16 output pre-scaled by dinv =========
__global__ __launch_bounds__(256) void gemm64_bf16s(const float* __restrict__ X,
                                                    const float* __restrict__ W,
                                                    const float* __restrict__ dinv,
                                                    unsigned short* __restrict__ xs, int n) {
    __shared__ float sX[64][68];
    __shared__ float sW[64 * 64];
    int t = threadIdx.x;
    int base = blockIdx.x * 64;
    #pragma unroll
    for (int i = 0; i < 4; ++i) {
        int f = t * 4 + i * 1024;
        *(float4*)&sW[f] = *(const float4*)&W[f];
        int r = f >> 6, c = f & 63;
        int row = base + r;
        float4 xv = (row < n) ? *(const float4*)&X[(size_t)row * D + c]
                              : make_float4(0.f, 0.f, 0.f, 0.f);
        *(float4*)&sX[r][c] = xv;
    }
    __syncthreads();

    int cg = t & 15, rg = t >> 4;
    int j0 = cg * 4, r0 = rg * 4;
    float acc[4][4];
    #pragma unroll
    for (int a = 0; a < 4; ++a)
        #pragma unroll
        for (int c = 0; c < 4; ++c) acc[a][c] = 0.0f;

    #pragma unroll 4
    for (int kk = 0; kk < 64; kk += 4) {
        float4 w0 = *(const float4*)&sW[(kk + 0) * 64 + j0];
        float4 w1 = *(const float4*)&sW[(kk + 1) * 64 + j0];
        float4 w2 = *(const float4*)&sW[(kk + 2) * 64 + j0];
        float4 w3 = *(const float4*)&sW[(kk + 3) * 64 + j0];
        #pragma unroll
        for (int a = 0; a < 4; ++a) {
            float4 xv = *(const float4*)&sX[r0 + a][kk];
            acc[a][0] = fmaf(xv.x, w0.x, acc[a][0]); acc[a][1] = fmaf(xv.x, w0.y, acc[a][1]);
            acc[a][2] = fmaf(xv.x, w0.z, acc[a][2]); acc[a][3] = fmaf(xv.x, w0.w, acc[a][3]);
            acc[a][0] = fmaf(xv.y, w1.x, acc[a][0]); acc[a][1] = fmaf(xv.y, w1.y, acc[a][1]);
            acc[a][2] = fmaf(xv.y, w1.z, acc[a][2]); acc[a][3] = fmaf(xv.y, w1.w, acc[a][3]);
            acc[a][0] = fmaf(xv.z, w2.x, acc[a][0]); acc[a][1] = fmaf(xv.z, w2.y, acc[a][1]);
            acc[a][2] = fmaf(xv.z, w2.z, acc[a][2]); acc[a][3] = fmaf(xv.z, w2.w, acc[a][3]);
            acc[a][0] = fmaf(xv.w, w3.x, acc[a][0]); acc[a][1] = fmaf(xv.w, w3.y, acc[a][1]);
            acc[a][2] = fmaf(xv.w, w3.z, acc[a][2]); acc[a][3] = fmaf(xv.w, w3.w, acc[a][3]);
        }
    }

    #pragma unroll
    for (int a = 0; a < 4; ++a) {
        int row = base + r0 + a;
        if (row < n) {
            float dv = dinv[row];
            ushort4 h;
            h.x = f2bf(acc[a][0] * dv);
            h.y = f2bf(acc[a][1] * dv);
            h.z = f2bf(acc[a][2] * dv);
            h.w = f2bf(acc[a][3] * dv);
            *(ushort4*)&xs[(size_t)row * D + j0] = h;
        }
    }
}

// ====== fusedA: GCN1 gather (64 nodes, batch-8) -> 64x256 bf16-W GEMM ======
__global__ __launch_bounds__(512) void fusedA_kernel(const unsigned short* __restrict__ xs,
                                                     const float* __restrict__ dinv,
                                                     const int* __restrict__ rowptr,
                                                     const int* __restrict__ cnt,
                                                     const unsigned short* __restrict__ esrc,
                                                     const float* __restrict__ b1,
                                                     const float* __restrict__ Wq,
                                                     const float* __restrict__ bq,
                                                     const float* __restrict__ Wk,
                                                     const float* __restrict__ bk,
                                                     const float* __restrict__ Wv,
                                                     const float* __restrict__ bv,
                                                     const float* __restrict__ Ws,
                                                     const float* __restrict__ bs,
                                                     float* __restrict__ Yq,
                                                     unsigned short* __restrict__ kv,
                                                     float* __restrict__ Ysk, int n) {
    __shared__ float sX[64][68];
    __shared__ unsigned short sWt[256 * 72];   // [col 0..255][k 0..63] bf16, transposed
    int t = threadIdx.x;
    int base = blockIdx.x * 64;
    int local = t >> 3, sub = t & 7;
    int j0 = sub * 8;
    int node = base + local;

    // ---- stage 4 W mats transposed+bf16: sWt[(m*64+c)*72 + k] ----
    {
        int k0 = t >> 4;            // 0..31
        int c0 = (t & 15) * 4;
        #pragma unroll
        for (int m = 0; m < 4; ++m) {
            const float* W = (m == 0) ? Wq : (m == 1) ? Wk : (m == 2) ? Wv : Ws;
            #pragma unroll
            for (int h = 0; h < 2; ++h) {
                int k = k0 + 32 * h;
                float4 w = *(const float4*)&W[k * 64 + c0];
                sWt[(m * 64 + c0 + 0) * 72 + k] = f2bf(w.x);
                sWt[(m * 64 + c0 + 1) * 72 + k] = f2bf(w.y);
                sWt[(m * 64 + c0 + 2) * 72 + k] = f2bf(w.z);
                sWt[(m * 64 + c0 + 3) * 72 + k] = f2bf(w.w);
            }
        }
    }

    // ---- gather phase: each 8-lane group owns ONE node, batch-8 loads ----
    {
        float a[8] = {0.f, 0.f, 0.f, 0.f, 0.f, 0.f, 0.f, 0.f};
        float4 o0 = make_float4(0.f, 0.f, 0.f, 0.f);
        float4 o1 = make_float4(0.f, 0.f, 0.f, 0.f);
        if (node < n) {
            float dd = dinv[node];
            int start = rowptr[node], deg = cnt[node];
            uint4 sr = *(const uint4*)&xs[(size_t)node * D + j0];   // self term
            a[0] += BF_LO(sr.x); a[1] += BF_HI(sr.x);
            a[2] += BF_LO(sr.y); a[3] += BF_HI(sr.y);
            a[4] += BF_LO(sr.z); a[5] += BF_HI(sr.z);
            a[6] += BF_LO(sr.w); a[7] += BF_HI(sr.w);
            int i = 0;
            for (; i + 8 <= deg; i += 8) {
                uint4 r[8];
                #pragma unroll
                for (int u = 0; u < 8; ++u) {
                    int s = esrc[start + i + u];
                    r[u] = *(const uint4*)&xs[(size_t)s * D + j0];
                }
                #pragma unroll
                for (int u = 0; u < 8; ++u) {
                    a[0] += BF_LO(r[u].x); a[1] += BF_HI(r[u].x);
                    a[2] += BF_LO(r[u].y); a[3] += BF_HI(r[u].y);
                    a[4] += BF_LO(r[u].z); a[5] += BF_HI(r[u].z);
                    a[6] += BF_LO(r[u].w); a[7] += BF_HI(r[u].w);
                }
            }
            for (; i < deg; ++i) {
                int s = esrc[start + i];
                uint4 r = *(const uint4*)&xs[(size_t)s * D + j0];
                a[0] += BF_LO(r.x); a[1] += BF_HI(r.x);
                a[2] += BF_LO(r.y); a[3] += BF_HI(r.y);
                a[4] += BF_LO(r.z); a[5] += BF_HI(r.z);
                a[6] += BF_LO(r.w); a[7] += BF_HI(r.w);
            }
            float4 bb0 = *(const float4*)&b1[j0];
            float4 bb1 = *(const float4*)&b1[j0 + 4];
            o0.x = fmaxf(fmaf(dd, a[0], bb0.x), 0.f);
            o0.y = fmaxf(fmaf(dd, a[1], bb0.y), 0.f);
            o0.z = fmaxf(fmaf(dd, a[2], bb0.z), 0.f);
            o0.w = fmaxf(fmaf(dd, a[3], bb0.w), 0.f);
            o1.x = fmaxf(fmaf(dd, a[4], bb1.x), 0.f);
            o1.y = fmaxf(fmaf(dd, a[5], bb1.y), 0.f);
            o1.z = fmaxf(fmaf(dd, a[6], bb1.z), 0.f);
            o1.w = fmaxf(fmaf(dd, a[7], bb1.w), 0.f);
        }
        *(float4*)&sX[local][j0] = o0;
        *(float4*)&sX[local][j0 + 4] = o1;
    }
    __syncthreads();

    // ---- GEMM: [64 rows] x [64 k] @ [256 cols]; tile 4 rows x 8 cols ----
    // rows: rg + 16a (stride-16, bank-friendly); cols: cg + 32j (stride-32)
    int rg = t >> 5;      // 0..15
    int cg = t & 31;      // 0..31
    float acc[4][8];
    #pragma unroll
    for (int a = 0; a < 4; ++a)
        #pragma unroll
        for (int j = 0; j < 8; ++j) acc[a][j] = 0.0f;

    #pragma unroll 2
    for (int s = 0; s < 8; ++s) {          // 8-k chunks
        float xv[4][8];
        #pragma unroll
        for (int a = 0; a < 4; ++a) {
            int row = rg + 16 * a;
            float4 x0 = *(const float4*)&sX[row][s * 8];
            float4 x1 = *(const float4*)&sX[row][s * 8 + 4];
            xv[a][0] = x0.x; xv[a][1] = x0.y; xv[a][2] = x0.z; xv[a][3] = x0.w;
            xv[a][4] = x1.x; xv[a][5] = x1.y; xv[a][6] = x1.z; xv[a][7] = x1.w;
        }
        #pragma unroll
        for (int j = 0; j < 8; ++j) {
            uint4 wc = *(const uint4*)&sWt[(cg + 32 * j) * 72 + s * 8];
            float w0 = BF_LO(wc.x), w1 = BF_HI(wc.x);
            float w2 = BF_LO(wc.y), w3 = BF_HI(wc.y);
            float w4 = BF_LO(wc.z), w5 = BF_HI(wc.z);
            float w6 = BF_LO(wc.w), w7 = BF_HI(wc.w);
            #pragma unroll
            for (int a = 0; a < 4; ++a) {
                acc[a][j] = fmaf(xv[a][0], w0, acc[a][j]);
                acc[a][j] = fmaf(xv[a][1], w1, acc[a][j]);
                acc[a][j] = fmaf(xv[a][2], w2, acc[a][j]);
                acc[a][j] = fmaf(xv[a][3], w3, acc[a][j]);
                acc[a][j] = fmaf(xv[a][4], w4, acc[a][j]);
                acc[a][j] = fmaf(xv[a][5], w5, acc[a][j]);
                acc[a][j] = fmaf(xv[a][6], w6, acc[a][j]);
                acc[a][j] = fmaf(xv[a][7], w7, acc[a][j]);
            }
        }
    }

    // ---- epilogue: j0,1 -> q; j2,3 -> k; j4,5 -> v; j6,7 -> skip ----
    float bq0 = bq[cg], bq1 = bq[cg + 32];
    float bk0 = bk[cg], bk1 = bk[cg + 32];
    float bv0 = bv[cg], bv1 = bv[cg + 32];
    float bs0 = bs[cg], bs1 = bs[cg + 32];
    #pragma unroll
    for (int a = 0; a < 4; ++a) {
        int row = base + rg + 16 * a;
        if (row < n) {
            Yq[(size_t)row * 64 + cg]        = (acc[a][0] + bq0) * 0.125f;
            Yq[(size_t)row * 64 + cg + 32]   = (acc[a][1] + bq1) * 0.125f;
            kv[(size_t)row * 128 + cg]       = f2bf(acc[a][2] + bk0);
            kv[(size_t)row * 128 + cg + 32]  = f2bf(acc[a][3] + bk1);
            kv[(size_t)row * 128 + 64 + cg]      = f2bf(acc[a][4] + bv0);
            kv[(size_t)row * 128 + 64 + cg + 32] = f2bf(acc[a][5] + bv1);
            Ysk[(size_t)row * 64 + cg]       = acc[a][6] + bs0;
            Ysk[(size_t)row * 64 + cg + 32]  = acc[a][7] + bs1;
        }
    }
}

// ====== fusedB: attn gather (64 nodes, batch-8 phased) -> bf16-W2 GEMM =====
__global__ __launch_bounds__(512) void fusedB_kernel(const float* __restrict__ q,
                                                     const unsigned short* __restrict__ kv,
                                                     const float* __restrict__ skip,
                                                     const float* __restrict__ dinv,
                                                     const int* __restrict__ rowptr,
                                                     const int* __restrict__ cnt,
                                                     const unsigned short* __restrict__ esrc,
                                                     const float* __restrict__ W2,
                                                     unsigned short* __restrict__ xs2, int n) {
    __shared__ float sX[64][68];
    __shared__ unsigned short sWt[64 * 72];    // W2 transposed bf16
    int t = threadIdx.x;
    int base = blockIdx.x * 64;
    int local = t >> 3, sub = t & 7;
    int j0 = sub * 8;
    int node = base + local;

    // ---- stage W2 transposed+bf16 ----
    {
        int k0 = t >> 4;            // 0..31
        int c0 = (t & 15) * 4;
        #pragma unroll
        for (int h = 0; h < 2; ++h) {
            int k = k0 + 32 * h;
            float4 w = *(const float4*)&W2[k * 64 + c0];
            sWt[(c0 + 0) * 72 + k] = f2bf(w.x);
            sWt[(c0 + 1) * 72 + k] = f2bf(w.y);
            sWt[(c0 + 2) * 72 + k] = f2bf(w.z);
            sWt[(c0 + 3) * 72 + k] = f2bf(w.w);
        }
    }

    // ---- attn gather: plain exp, batch-8 (k phase -> v phase) ----
    {
        float4 o0 = make_float4(0.f, 0.f, 0.f, 0.f);
        float4 o1 = make_float4(0.f, 0.f, 0.f, 0.f);
        if (node < n) {
            int start = rowptr[node], deg = cnt[node];
            float4 q0 = *(const float4*)&q[(size_t)node * D + j0];     // pre-scaled 1/8
            float4 q1 = *(const float4*)&q[(size_t)node * D + j0 + 4];
            float4 s0 = *(const float4*)&skip[(size_t)node * D + j0];
            float4 s1 = *(const float4*)&skip[(size_t)node * D + j0 + 4];
            float z = 0.0f;
            float a[8] = {0.f, 0.f, 0.f, 0.f, 0.f, 0.f, 0.f, 0.f};
            int i = 0;
            for (; i + 8 <= deg; i += 8) {
                size_t ro[8];
                #pragma unroll
                for (int u = 0; u < 8; ++u)
                    ro[u] = (size_t)esrc[start + i + u] * 128;
                float w[8];
                {
                    uint4 kr[8];
                    #pragma unroll
                    for (int u = 0; u < 8; ++u)
                        kr[u] = *(const uint4*)&kv[ro[u] + j0];
                    float p[8];
                    #pragma unroll
                    for (int u = 0; u < 8; ++u)
                        p[u] = q0.x * BF_LO(kr[u].x) + q0.y * BF_HI(kr[u].x)
                             + q0.z * BF_LO(kr[u].y) + q0.w * BF_HI(kr[u].y)
                             + q1.x * BF_LO(kr[u].z) + q1.y * BF_HI(kr[u].z)
                             + q1.z * BF_LO(kr[u].w) + q1.w * BF_HI(kr[u].w);
                    #pragma unroll
                    for (int off = 1; off < 8; off <<= 1) {
                        #pragma unroll
                        for (int u = 0; u < 8; ++u) p[u] += __shfl_xor(p[u], off, 64);
                    }
                    #pragma unroll
                    for (int u = 0; u < 8; ++u) {
                        w[u] = __expf(p[u]);
                        z += w[u];
                    }
                }
                {
                    uint4 vr[8];
                    #pragma unroll
                    for (int u = 0; u < 8; ++u)
                        vr[u] = *(const uint4*)&kv[ro[u] + 64 + j0];
                    #pragma unroll
                    for (int u = 0; u < 8; ++u) {
                        a[0] = fmaf(w[u], BF_LO(vr[u].x), a[0]);
                        a[1] = fmaf(w[u], BF_HI(vr[u].x), a[1]);
                        a[2] = fmaf(w[u], BF_LO(vr[u].y), a[2]);
                        a[3] = fmaf(w[u], BF_HI(vr[u].y), a[3]);
                        a[4] = fmaf(w[u], BF_LO(vr[u].z), a[4]);
                        a[5] = fmaf(w[u], BF_HI(vr[u].z), a[5]);
                        a[6] = fmaf(w[u], BF_LO(vr[u].w), a[6]);
                        a[7] = fmaf(w[u], BF_HI(vr[u].w), a[7]);
                    }
                }
            }
            for (; i < deg; ++i) {
                size_t ro = (size_t)esrc[start + i] * 128;
                uint4 kr = *(const uint4*)&kv[ro + j0];
                uint4 vr = *(const uint4*)&kv[ro + 64 + j0];
                float p = q0.x * BF_LO(kr.x) + q0.y * BF_HI(kr.x)
                        + q0.z * BF_LO(kr.y) + q0.w * BF_HI(kr.y)
                        + q1.x * BF_LO(kr.z) + q1.y * BF_HI(kr.z)
                        + q1.z * BF_LO(kr.w) + q1.w * BF_HI(kr.w);
                #pragma unroll
                for (int off = 1; off < 8; off <<= 1) p += __shfl_xor(p, off, 64);
                float w = __expf(p);
                z += w;
                a[0] = fmaf(w, BF_LO(vr.x), a[0]); a[1] = fmaf(w, BF_HI(vr.x), a[1]);
                a[2] = fmaf(w, BF_LO(vr.y), a[2]); a[3] = fmaf(w, BF_HI(vr.y), a[3]);
                a[4] = fmaf(w, BF_LO(vr.z), a[4]); a[5] = fmaf(w, BF_HI(vr.z), a[5]);
                a[6] = fmaf(w, BF_LO(vr.w), a[6]); a[7] = fmaf(w, BF_HI(vr.w), a[7]);
            }
            if (deg > 0) {
                float inv = 1.0f / z;
                o0.x = fmaf(a[0], inv, s0.x); o0.y = fmaf(a[1], inv, s0.y);
                o0.z = fmaf(a[2], inv, s0.z); o0.w = fmaf(a[3], inv, s0.w);
                o1.x = fmaf(a[4], inv, s1.x); o1.y = fmaf(a[5], inv, s1.y);
                o1.z = fmaf(a[6], inv, s1.z); o1.w = fmaf(a[7], inv, s1.w);
            } else {
                o0 = s0; o1 = s1;
            }
        }
        *(float4*)&sX[local][j0] = o0;
        *(float4*)&sX[local][j0 + 4] = o1;
    }
    __syncthreads();

    // ---- GEMM: [64 x 64] @ W2; tile 2 rows x 4 cols ----
    // rows: rg + 32a (stride-32); cols: cg + 16j (stride-16)
    int rg = t >> 4;      // 0..31
    int cg = t & 15;      // 0..15
    float acc[2][4];
    #pragma unroll
    for (int a = 0; a < 2; ++a)
        #pragma unroll
        for (int j = 0; j < 4; ++j) acc[a][j] = 0.0f;

    #pragma unroll 2
    for (int s = 0; s < 8; ++s) {
        float xv[2][8];
        #pragma unroll
        for (int a = 0; a < 2; ++a) {
            int row = rg + 32 * a;
            float4 x0 = *(const float4*)&sX[row][s * 8];
            float4 x1 = *(const float4*)&sX[row][s * 8 + 4];
            xv[a][0] = x0.x; xv[a][1] = x0.y; xv[a][2] = x0.z; xv[a][3] = x0.w;
            xv[a][4] = x1.x; xv[a][5] = x1.y; xv[a][6] = x1.z; xv[a][7] = x1.w;
        }
        #pragma unroll
        for (int j = 0; j < 4; ++j) {
            uint4 wc = *(const uint4*)&sWt[(cg + 16 * j) * 72 + s * 8];
            float w0 = BF_LO(wc.x), w1 = BF_HI(wc.x);
            float w2 = BF_LO(wc.y), w3 = BF_HI(wc.y);
            float w4 = BF_LO(wc.z), w5 = BF_HI(wc.z);
            float w6 = BF_LO(wc.w), w7 = BF_HI(wc.w);
            #pragma unroll
            for (int a = 0; a < 2; ++a) {
                acc[a][j] = fmaf(xv[a][0], w0, acc[a][j]);
                acc[a][j] = fmaf(xv[a][1], w1, acc[a][j]);
                acc[a][j] = fmaf(xv[a][2], w2, acc[a][j]);
                acc[a][j] = fmaf(xv[a][3], w3, acc[a][j]);
                acc[a][j] = fmaf(xv[a][4], w4, acc[a][j]);
                acc[a][j] = fmaf(xv[a][5], w5, acc[a][j]);
                acc[a][j] = fmaf(xv[a][6], w6, acc[a][j]);
                acc[a][j] = fmaf(xv[a][7], w7, acc[a][j]);
            }
        }
    }

    #pragma unroll
    for (int a = 0; a < 2; ++a) {
        int row = base + rg + 32 * a;
        if (row < n) {
            float dv = dinv[row];
            #pragma unroll
            for (int j = 0; j < 4; ++j)
                xs2[(size_t)row * 64 + cg + 16 * j] = f2bf(acc[a][j] * dv);
        }
    }
}

// ===================== GCN gather (bf16 rows, 8x8 grouped) =================
__global__ __launch_bounds__(256) void gcn_gather_kernel(const unsigned short* __restrict__ xs,
                                                         const float* __restrict__ dinv,
                                                         const int* __restrict__ rowptr,
                                                         const int* __restrict__ cnt,
                                                         const unsigned short* __restrict__ esrc,
                                                         const float* __restrict__ bias,
                                                         float* __restrict__ out,
                                                         int n, int relu) {
    int node = (blockIdx.x * blockDim.x + threadIdx.x) >> 6;
    if (node >= n) return;
    int lane = threadIdx.x & 63;
    int grp = lane >> 3;
    int sub = lane & 7;
    int j0 = sub * 8;

    int start = rowptr[node], deg = cnt[node];

    float a[8] = {0.f, 0.f, 0.f, 0.f, 0.f, 0.f, 0.f, 0.f};
    int i = grp;
    int sNext = (i < deg) ? esrc[start + i] : 0;
    for (; i < deg; i += 8) {
        int s = sNext;
        int in = i + 8;
        if (in < deg) sNext = esrc[start + in];
        uint4 r = *(const uint4*)&xs[(size_t)s * D + j0];
        a[0] += BF_LO(r.x); a[1] += BF_HI(r.x);
        a[2] += BF_LO(r.y); a[3] += BF_HI(r.y);
        a[4] += BF_LO(r.z); a[5] += BF_HI(r.z);
        a[6] += BF_LO(r.w); a[7] += BF_HI(r.w);
    }
    #pragma unroll
    for (int off = 8; off < 64; off <<= 1) {
        #pragma unroll
        for (int c = 0; c < 8; ++c) a[c] += __shfl_xor(a[c], off, 64);
    }

    if (grp == 0) {
        float dd = dinv[node];
        uint4 sr = *(const uint4*)&xs[(size_t)node * D + j0];
        a[0] += BF_LO(sr.x); a[1] += BF_HI(sr.x);
        a[2] += BF_LO(sr.y); a[3] += BF_HI(sr.y);
        a[4] += BF_LO(sr.z); a[5] += BF_HI(sr.z);
        a[6] += BF_LO(sr.w); a[7] += BF_HI(sr.w);
        float4 b0 = *(const float4*)&bias[j0];
        float4 b1 = *(const float4*)&bias[j0 + 4];
        float o[8];
        o[0] = fmaf(dd, a[0], b0.x); o[1] = fmaf(dd, a[1], b0.y);
        o[2] = fmaf(dd, a[2], b0.z); o[3] = fmaf(dd, a[3], b0.w);
        o[4] = fmaf(dd, a[4], b1.x); o[5] = fmaf(dd, a[5], b1.y);
        o[6] = fmaf(dd, a[6], b1.z); o[7] = fmaf(dd, a[7], b1.w);
        if (relu) {
            #pragma unroll
            for (int c = 0; c < 8; ++c) o[c] = fmaxf(o[c], 0.f);
        }
        *(float4*)&out[(size_t)node * D + j0] = make_float4(o[0], o[1], o[2], o[3]);
        *(float4*)&out[(size_t)node * D + j0 + 4] = make_float4(o[4], o[5], o[6], o[7]);
    }
}

// =============================== launch ====================================

extern "C" void kernel_launch(void* const* d_in, const int* in_sizes, int n_in,
                              void* d_out, int out_size, void* d_ws, size_t ws_size,
                              hipStream_t stream) {
    const float* x  = (const float*)d_in[0];
    const int*   ei = (const int*)d_in[1];
    const float* W1 = (const float*)d_in[2];
    const float* b1 = (const float*)d_in[3];
    const float* Wq = (const float*)d_in[4];
    const float* bq = (const float*)d_in[5];
    const float* Wk = (const float*)d_in[6];
    const float* bk = (const float*)d_in[7];
    const float* Wv = (const float*)d_in[8];
    const float* bv = (const float*)d_in[9];
    const float* Ws = (const float*)d_in[10];
    const float* bs = (const float*)d_in[11];
    const float* W2 = (const float*)d_in[12];
    const float* b2 = (const float*)d_in[13];
    float* out = (float*)d_out;

    const int n = in_sizes[0] / D;   // 50000  (< 65536 for 16-bit packing)
    const int e = in_sizes[1] / 2;   // 800000
    const int* src = ei;
    const int* dst = ei + e;
    const int n64 = n * D;
    const int nbkt = (n + (1 << BKT_SHIFT) - 1) >> BKT_SHIFT;   // 98

    char* w = (char*)d_ws;
    auto carve = [&](size_t bytes) {
        char* p = w;
        w += (bytes + 255) & ~(size_t)255;
        return p;
    };
    int* gcursor            = (int*)carve(128 * 4);
    unsigned int* staging   = (unsigned int*)carve((size_t)nbkt * CAP * 4);
    unsigned short* esrc    = (unsigned short*)carve((size_t)e * 2);
    int* cnt                = (int*)carve((size_t)n * 4);
    int* rowptr             = (int*)carve((size_t)n * 4);
    float* dinv             = (float*)carve((size_t)n * 4);
    float* bufQ             = (float*)carve((size_t)n64 * 4);   // q (pre-scaled)
    unsigned short* xs      = (unsigned short*)carve((size_t)n64 * 2);  // bf16 staging
    unsigned short* kv      = (unsigned short*)carve((size_t)n64 * 4);  // k|v bf16

    const int nb_binA = (e + CHUNK - 1) / CHUNK;   // 196
    const int nb_nw   = (n + 3) / 4;               // wave-per-node (final gather)
    const int nb_g    = (n + 63) / 64;             // 64 rows/block

    // ---- CSR build (2-phase binning) ----
    init_gcursor<<<1, 128, 0, stream>>>(gcursor);
    binA_kernel<<<nb_binA, 256, 0, stream>>>(src, dst, gcursor, staging, e, nbkt);
    binB_kernel<<<nbkt, 256, 0, stream>>>(gcursor, staging, esrc, cnt, rowptr, dinv, n, nbkt);

    // ---- layer 1 GEMM: xs = bf16((x@W1)*dinv) ----
    gemm64_bf16s<<<nb_g, 256, 0, stream>>>(x, W1, dinv, xs, n);

    // ---- fused: GCN1 gather -> x1 (LDS) -> QKVS GEMM (bf16 W) ----
    fusedA_kernel<<<nb_g, 512, 0, stream>>>(xs, dinv, rowptr, cnt, esrc, b1,
                                            Wq, bq, Wk, bk, Wv, bv, Ws, bs,
                                            bufQ, kv, out, n);   // skip -> out

    // ---- fused: attn gather -> x2 (LDS) -> W2 GEMM (bf16 W) -> xs ----
    fusedB_kernel<<<nb_g, 512, 0, stream>>>(bufQ, kv, out, dinv,
                                            rowptr, cnt, esrc, W2, xs, n);

    // ---- final GCN2 gather -> out ----
    gcn_gather_kernel<<<nb_nw, 256, 0, stream>>>(xs, dinv, rowptr, cnt, esrc,
                                                 b2, out, n, 0);
}

// Round 14
// 235.490 us; speedup vs baseline: 1.0677x; 1.0677x over previous
//
#include <hip/hip_runtime.h>
#include <math.h>

// ---------------------------------------------------------------------------
// GraphTransformer: GCNConv(64->64)+ReLU -> TransformerConv(h=1) -> GCNConv(64->64)
// N=50000, E=800000, D=64, fp32 in/out.
// Round 14: fused GEMM phases -> MFMA (v_mfma_f32_16x16x32_bf16). x1/x2
// staged in LDS as bf16; W transposed bf16. A-frag/B-frag = single
// ds_read_b128 each; C/D layout col=lane&15, row=quad*4+reg. Gathers/CSR
// identical to R12 (known-good 241.7us baseline).
// ---------------------------------------------------------------------------

#define D 64
#define BKT_SHIFT 9
#define CAP 12288
#define CHUNK 4096

typedef __attribute__((ext_vector_type(8))) short short8;
typedef __attribute__((ext_vector_type(4))) float f32x4;

__device__ __forceinline__ unsigned short f2bf(float f) {
    unsigned int u = __float_as_uint(f);
    u += 0x7FFFu + ((u >> 16) & 1u);
    return (unsigned short)(u >> 16);
}
#define BF_LO(u) __uint_as_float((u) << 16)
#define BF_HI(u) __uint_as_float((u) & 0xFFFF0000u)

__device__ __forceinline__ unsigned int pack2(float a, float b) {
    return (unsigned int)f2bf(a) | ((unsigned int)f2bf(b) << 16);
}

// ============================ CSR build ====================================

__global__ void init_gcursor(int* __restrict__ gcursor) {
    if (threadIdx.x < 128) gcursor[threadIdx.x] = 0;
}

__global__ __launch_bounds__(256) void binA_kernel(const int* __restrict__ src,
                                                   const int* __restrict__ dst,
                                                   int* __restrict__ gcursor,
                                                   unsigned int* __restrict__ staging,
                                                   int e, int nbkt) {
    __shared__ int cntB[128];
    __shared__ int offB[128];
    __shared__ int curB[128];
    __shared__ int gbase[128];
    __shared__ unsigned int pairs[CHUNK];
    __shared__ unsigned char bkt[CHUNK];

    int t = threadIdx.x;
    int e0 = blockIdx.x * CHUNK;
    int ecnt = min(CHUNK, e - e0);

    if (t < 128) cntB[t] = 0;
    __syncthreads();

    int myS[CHUNK / 256], myD[CHUNK / 256];
    #pragma unroll
    for (int i = 0; i < CHUNK / 256; ++i) {
        int idx = t + 256 * i;
        if (idx < ecnt) {
            myS[i] = src[e0 + idx];
            myD[i] = dst[e0 + idx];
            atomicAdd(&cntB[myD[i] >> BKT_SHIFT], 1);
        }
    }
    __syncthreads();
    if (t < 128) offB[t] = cntB[t];
    __syncthreads();
    for (int off = 1; off < 128; off <<= 1) {
        int add = (t < 128 && t >= off) ? offB[t - off] : 0;
        __syncthreads();
        if (t < 128) offB[t] += add;
        __syncthreads();
    }
    if (t < 128) {
        int excl = offB[t] - cntB[t];
        offB[t] = excl;
        curB[t] = excl;
        if (t < nbkt && cntB[t] > 0) gbase[t] = atomicAdd(&gcursor[t], cntB[t]);
    }
    __syncthreads();
    #pragma unroll
    for (int i = 0; i < CHUNK / 256; ++i) {
        int idx = t + 256 * i;
        if (idx < ecnt) {
            int b = myD[i] >> BKT_SHIFT;
            int p = atomicAdd(&curB[b], 1);
            pairs[p] = ((unsigned int)myD[i] << 16) | (unsigned int)myS[i];
            bkt[p] = (unsigned char)b;
        }
    }
    __syncthreads();
    for (int p = t; p < ecnt; p += 256) {
        int b = bkt[p];
        staging[(size_t)b * CAP + gbase[b] + (p - offB[b])] = pairs[p];
    }
}

__global__ __launch_bounds__(256) void binB_kernel(const int* __restrict__ gcursor,
                                                   const unsigned int* __restrict__ staging,
                                                   unsigned short* __restrict__ esrc,
                                                   int* __restrict__ cnt,
                                                   int* __restrict__ rowptr,
                                                   float* __restrict__ dinv,
                                                   int n, int nbkt) {
    __shared__ int bpre[128];
    __shared__ int c512[512];
    __shared__ int o512[512];
    int t = threadIdx.x;
    int b = blockIdx.x;

    if (t < 128) bpre[t] = (t < nbkt) ? gcursor[t] : 0;
    __syncthreads();
    for (int off = 1; off < 128; off <<= 1) {
        int add = (t < 128 && t >= off) ? bpre[t - off] : 0;
        __syncthreads();
        if (t < 128) bpre[t] += add;
        __syncthreads();
    }
    int base_b = (b == 0) ? 0 : bpre[b - 1];
    int cnt_b = gcursor[b];
    int lo = b << BKT_SHIFT;

    c512[t] = 0; c512[t + 256] = 0;
    __syncthreads();
    const unsigned int* st = staging + (size_t)b * CAP;
    for (int i = t; i < cnt_b; i += 256)
        atomicAdd(&c512[(int)(st[i] >> 16) - lo], 1);
    __syncthreads();
    o512[t] = c512[t]; o512[t + 256] = c512[t + 256];
    __syncthreads();
    for (int off = 1; off < 512; off <<= 1) {
        int a1 = (t >= off) ? o512[t - off] : 0;
        int a2 = o512[t + 256 - off];
        __syncthreads();
        o512[t] += a1; o512[t + 256] += a2;
        __syncthreads();
    }
    int e1 = o512[t] - c512[t];
    int e2 = o512[t + 256] - c512[t + 256];
    __syncthreads();
    o512[t] = e1; o512[t + 256] = e2;
    __syncthreads();
    for (int i = t; i < 512; i += 256) {
        int g = lo + i;
        if (g < n) {
            int c = c512[i];
            cnt[g] = c;
            rowptr[g] = base_b + o512[i];
            dinv[g] = rsqrtf((float)c + 1.0f);
        }
    }
    __syncthreads();
    for (int i = t; i < cnt_b; i += 256) {
        unsigned int pk = st[i];
        int local = (int)(pk >> 16) - lo;
        int p = atomicAdd(&o512[local], 1);
        esrc[base_b + p] = (unsigned short)(pk & 0xFFFFu);
    }
}

// ============ GEMM 64x64, epilogue: bf16 output pre-scaled by dinv =========
__global__ __launch_bounds__(256) void gemm64_bf16s(const float* __restrict__ X,
                                                    const float* __restrict__ W,
                                                    const float* __restrict__ dinv,
                                                    unsigned short* __restrict__ xs, int n) {
    __shared__ float sX[64][68];
    __shared__ float sW[64 * 64];
    int t = threadIdx.x;
    int base = blockIdx.x * 64;
    #pragma unroll
    for (int i = 0; i < 4; ++i) {
        int f = t * 4 + i * 1024;
        *(float4*)&sW[f] = *(const float4*)&W[f];
        int r = f >> 6, c = f & 63;
        int row = base + r;
        float4 xv = (row < n) ? *(const float4*)&X[(size_t)row * D + c]
                              : make_float4(0.f, 0.f, 0.f, 0.f);
        *(float4*)&sX[r][c] = xv;
    }
    __syncthreads();

    int cg = t & 15, rg = t >> 4;
    int j0 = cg * 4, r0 = rg * 4;
    float acc[4][4];
    #pragma unroll
    for (int a = 0; a < 4; ++a)
        #pragma unroll
        for (int c = 0; c < 4; ++c) acc[a][c] = 0.0f;

    #pragma unroll 4
    for (int kk = 0; kk < 64; kk += 4) {
        float4 w0 = *(const float4*)&sW[(kk + 0) * 64 + j0];
        float4 w1 = *(const float4*)&sW[(kk + 1) * 64 + j0];
        float4 w2 = *(const float4*)&sW[(kk + 2) * 64 + j0];
        float4 w3 = *(const float4*)&sW[(kk + 3) * 64 + j0];
        #pragma unroll
        for (int a = 0; a < 4; ++a) {
            float4 xv = *(const float4*)&sX[r0 + a][kk];
            acc[a][0] = fmaf(xv.x, w0.x, acc[a][0]); acc[a][1] = fmaf(xv.x, w0.y, acc[a][1]);
            acc[a][2] = fmaf(xv.x, w0.z, acc[a][2]); acc[a][3] = fmaf(xv.x, w0.w, acc[a][3]);
            acc[a][0] = fmaf(xv.y, w1.x, acc[a][0]); acc[a][1] = fmaf(xv.y, w1.y, acc[a][1]);
            acc[a][2] = fmaf(xv.y, w1.z, acc[a][2]); acc[a][3] = fmaf(xv.y, w1.w, acc[a][3]);
            acc[a][0] = fmaf(xv.z, w2.x, acc[a][0]); acc[a][1] = fmaf(xv.z, w2.y, acc[a][1]);
            acc[a][2] = fmaf(xv.z, w2.z, acc[a][2]); acc[a][3] = fmaf(xv.z, w2.w, acc[a][3]);
            acc[a][0] = fmaf(xv.w, w3.x, acc[a][0]); acc[a][1] = fmaf(xv.w, w3.y, acc[a][1]);
            acc[a][2] = fmaf(xv.w, w3.z, acc[a][2]); acc[a][3] = fmaf(xv.w, w3.w, acc[a][3]);
        }
    }

    #pragma unroll
    for (int a = 0; a < 4; ++a) {
        int row = base + r0 + a;
        if (row < n) {
            float dv = dinv[row];
            ushort4 h;
            h.x = f2bf(acc[a][0] * dv);
            h.y = f2bf(acc[a][1] * dv);
            h.z = f2bf(acc[a][2] * dv);
            h.w = f2bf(acc[a][3] * dv);
            *(ushort4*)&xs[(size_t)row * D + j0] = h;
        }
    }
}

// ====== fusedA: GCN1 gather (64 nodes, batch-8) -> MFMA QKVS GEMM ==========
__global__ __launch_bounds__(512) void fusedA_kernel(const unsigned short* __restrict__ xs,
                                                     const float* __restrict__ dinv,
                                                     const int* __restrict__ rowptr,
                                                     const int* __restrict__ cnt,
                                                     const unsigned short* __restrict__ esrc,
                                                     const float* __restrict__ b1,
                                                     const float* __restrict__ Wq,
                                                     const float* __restrict__ bq,
                                                     const float* __restrict__ Wk,
                                                     const float* __restrict__ bk,
                                                     const float* __restrict__ Wv,
                                                     const float* __restrict__ bv,
                                                     const float* __restrict__ Ws,
                                                     const float* __restrict__ bs,
                                                     float* __restrict__ Yq,
                                                     unsigned short* __restrict__ kv,
                                                     float* __restrict__ Ysk, int n) {
    __shared__ unsigned short sXb[64][72];      // x1 bf16, row stride 144B
    __shared__ unsigned short sWt[256 * 72];    // 4 W mats, [col][k] bf16
    int t = threadIdx.x;
    int base = blockIdx.x * 64;
    int local = t >> 3, sub = t & 7;
    int j0 = sub * 8;
    int node = base + local;

    // ---- stage 4 W mats transposed+bf16 ----
    {
        int k0 = t >> 4;            // 0..31
        int c0 = (t & 15) * 4;
        #pragma unroll
        for (int m = 0; m < 4; ++m) {
            const float* W = (m == 0) ? Wq : (m == 1) ? Wk : (m == 2) ? Wv : Ws;
            #pragma unroll
            for (int h = 0; h < 2; ++h) {
                int k = k0 + 32 * h;
                float4 w = *(const float4*)&W[k * 64 + c0];
                sWt[(m * 64 + c0 + 0) * 72 + k] = f2bf(w.x);
                sWt[(m * 64 + c0 + 1) * 72 + k] = f2bf(w.y);
                sWt[(m * 64 + c0 + 2) * 72 + k] = f2bf(w.z);
                sWt[(m * 64 + c0 + 3) * 72 + k] = f2bf(w.w);
            }
        }
    }

    // ---- gather phase (R12 batch-8), result packed bf16 into sXb ----
    {
        float a[8] = {0.f, 0.f, 0.f, 0.f, 0.f, 0.f, 0.f, 0.f};
        uint4 pk = make_uint4(0u, 0u, 0u, 0u);
        if (node < n) {
            float dd = dinv[node];
            int start = rowptr[node], deg = cnt[node];
            uint4 sr = *(const uint4*)&xs[(size_t)node * D + j0];   // self term
            a[0] += BF_LO(sr.x); a[1] += BF_HI(sr.x);
            a[2] += BF_LO(sr.y); a[3] += BF_HI(sr.y);
            a[4] += BF_LO(sr.z); a[5] += BF_HI(sr.z);
            a[6] += BF_LO(sr.w); a[7] += BF_HI(sr.w);
            int i = 0;
            for (; i + 8 <= deg; i += 8) {
                uint4 r[8];
                #pragma unroll
                for (int u = 0; u < 8; ++u) {
                    int s = esrc[start + i + u];
                    r[u] = *(const uint4*)&xs[(size_t)s * D + j0];
                }
                #pragma unroll
                for (int u = 0; u < 8; ++u) {
                    a[0] += BF_LO(r[u].x); a[1] += BF_HI(r[u].x);
                    a[2] += BF_LO(r[u].y); a[3] += BF_HI(r[u].y);
                    a[4] += BF_LO(r[u].z); a[5] += BF_HI(r[u].z);
                    a[6] += BF_LO(r[u].w); a[7] += BF_HI(r[u].w);
                }
            }
            for (; i < deg; ++i) {
                int s = esrc[start + i];
                uint4 r = *(const uint4*)&xs[(size_t)s * D + j0];
                a[0] += BF_LO(r.x); a[1] += BF_HI(r.x);
                a[2] += BF_LO(r.y); a[3] += BF_HI(r.y);
                a[4] += BF_LO(r.z); a[5] += BF_HI(r.z);
                a[6] += BF_LO(r.w); a[7] += BF_HI(r.w);
            }
            float4 bb0 = *(const float4*)&b1[j0];
            float4 bb1 = *(const float4*)&b1[j0 + 4];
            float o0 = fmaxf(fmaf(dd, a[0], bb0.x), 0.f);
            float o1 = fmaxf(fmaf(dd, a[1], bb0.y), 0.f);
            float o2 = fmaxf(fmaf(dd, a[2], bb0.z), 0.f);
            float o3 = fmaxf(fmaf(dd, a[3], bb0.w), 0.f);
            float o4 = fmaxf(fmaf(dd, a[4], bb1.x), 0.f);
            float o5 = fmaxf(fmaf(dd, a[5], bb1.y), 0.f);
            float o6 = fmaxf(fmaf(dd, a[6], bb1.z), 0.f);
            float o7 = fmaxf(fmaf(dd, a[7], bb1.w), 0.f);
            pk.x = pack2(o0, o1); pk.y = pack2(o2, o3);
            pk.z = pack2(o4, o5); pk.w = pack2(o6, o7);
        }
        *(uint4*)&sXb[local][j0] = pk;
    }
    __syncthreads();

    // ---- MFMA phase: [64 x 64] @ [64 x 256]; 64 tiles of 16x16, 8/wave ----
    int w = t >> 6;                 // wave 0..7
    int lane = t & 63;
    int l15 = lane & 15;
    int quad = lane >> 4;
    int rt = w & 3;                 // row-tile 0..3
    int ct0 = (w >> 2) * 8;         // col-tile base (0 or 8)

    // A fragments (shared across this wave's 8 tiles)
    short8 a0 = *(const short8*)&sXb[rt * 16 + l15][quad * 8];
    short8 a1 = *(const short8*)&sXb[rt * 16 + l15][32 + quad * 8];

    #pragma unroll
    for (int tt = 0; tt < 8; ++tt) {
        int ct = ct0 + tt;
        int gcol = ct * 16 + l15;           // 0..255
        const unsigned short* wcol = &sWt[(size_t)gcol * 72];
        short8 bfr0 = *(const short8*)&wcol[quad * 8];
        short8 bfr1 = *(const short8*)&wcol[32 + quad * 8];
        f32x4 acc = {0.f, 0.f, 0.f, 0.f};
        acc = __builtin_amdgcn_mfma_f32_16x16x32_bf16(a0, bfr0, acc, 0, 0, 0);
        acc = __builtin_amdgcn_mfma_f32_16x16x32_bf16(a1, bfr1, acc, 0, 0, 0);

        int m = gcol >> 6;                  // 0=q 1=k 2=v 3=skip (wave-uniform)
        int col = gcol & 63;
        if (m == 0) {
            float bb = bq[col];
            #pragma unroll
            for (int rgi = 0; rgi < 4; ++rgi) {
                int row = base + rt * 16 + quad * 4 + rgi;
                if (row < n) Yq[(size_t)row * 64 + col] = (acc[rgi] + bb) * 0.125f;
            }
        } else if (m == 1) {
            float bb = bk[col];
            #pragma unroll
            for (int rgi = 0; rgi < 4; ++rgi) {
                int row = base + rt * 16 + quad * 4 + rgi;
                if (row < n) kv[(size_t)row * 128 + col] = f2bf(acc[rgi] + bb);
            }
        } else if (m == 2) {
            float bb = bv[col];
            #pragma unroll
            for (int rgi = 0; rgi < 4; ++rgi) {
                int row = base + rt * 16 + quad * 4 + rgi;
                if (row < n) kv[(size_t)row * 128 + 64 + col] = f2bf(acc[rgi] + bb);
            }
        } else {
            float bb = bs[col];
            #pragma unroll
            for (int rgi = 0; rgi < 4; ++rgi) {
                int row = base + rt * 16 + quad * 4 + rgi;
                if (row < n) Ysk[(size_t)row * 64 + col] = acc[rgi] + bb;
            }
        }
    }
}

// ====== fusedB: attn gather (64 nodes, batch-8 phased) -> MFMA W2 GEMM =====
__global__ __launch_bounds__(512) void fusedB_kernel(const float* __restrict__ q,
                                                     const unsigned short* __restrict__ kv,
                                                     const float* __restrict__ skip,
                                                     const float* __restrict__ dinv,
                                                     const int* __restrict__ rowptr,
                                                     const int* __restrict__ cnt,
                                                     const unsigned short* __restrict__ esrc,
                                                     const float* __restrict__ W2,
                                                     unsigned short* __restrict__ xs2, int n) {
    __shared__ unsigned short sXb[64][72];     // x2 bf16
    __shared__ unsigned short sWt[64 * 72];    // W2 [col][k] bf16
    int t = threadIdx.x;
    int base = blockIdx.x * 64;
    int local = t >> 3, sub = t & 7;
    int j0 = sub * 8;
    int node = base + local;

    // ---- stage W2 transposed+bf16 ----
    {
        int k0 = t >> 4;            // 0..31
        int c0 = (t & 15) * 4;
        #pragma unroll
        for (int h = 0; h < 2; ++h) {
            int k = k0 + 32 * h;
            float4 w = *(const float4*)&W2[k * 64 + c0];
            sWt[(c0 + 0) * 72 + k] = f2bf(w.x);
            sWt[(c0 + 1) * 72 + k] = f2bf(w.y);
            sWt[(c0 + 2) * 72 + k] = f2bf(w.z);
            sWt[(c0 + 3) * 72 + k] = f2bf(w.w);
        }
    }

    // ---- attn gather (R12 batch-8 phased), result packed bf16 into sXb ----
    {
        uint4 pk = make_uint4(0u, 0u, 0u, 0u);
        if (node < n) {
            int start = rowptr[node], deg = cnt[node];
            float4 q0 = *(const float4*)&q[(size_t)node * D + j0];     // pre-scaled 1/8
            float4 q1 = *(const float4*)&q[(size_t)node * D + j0 + 4];
            float4 s0 = *(const float4*)&skip[(size_t)node * D + j0];
            float4 s1 = *(const float4*)&skip[(size_t)node * D + j0 + 4];
            float z = 0.0f;
            float a[8] = {0.f, 0.f, 0.f, 0.f, 0.f, 0.f, 0.f, 0.f};
            int i = 0;
            for (; i + 8 <= deg; i += 8) {
                size_t ro[8];
                #pragma unroll
                for (int u = 0; u < 8; ++u)
                    ro[u] = (size_t)esrc[start + i + u] * 128;
                float wgt[8];
                {
                    uint4 kr[8];
                    #pragma unroll
                    for (int u = 0; u < 8; ++u)
                        kr[u] = *(const uint4*)&kv[ro[u] + j0];
                    float p[8];
                    #pragma unroll
                    for (int u = 0; u < 8; ++u)
                        p[u] = q0.x * BF_LO(kr[u].x) + q0.y * BF_HI(kr[u].x)
                             + q0.z * BF_LO(kr[u].y) + q0.w * BF_HI(kr[u].y)
                             + q1.x * BF_LO(kr[u].z) + q1.y * BF_HI(kr[u].z)
                             + q1.z * BF_LO(kr[u].w) + q1.w * BF_HI(kr[u].w);
                    #pragma unroll
                    for (int off = 1; off < 8; off <<= 1) {
                        #pragma unroll
                        for (int u = 0; u < 8; ++u) p[u] += __shfl_xor(p[u], off, 64);
                    }
                    #pragma unroll
                    for (int u = 0; u < 8; ++u) {
                        wgt[u] = __expf(p[u]);
                        z += wgt[u];
                    }
                }
                {
                    uint4 vr[8];
                    #pragma unroll
                    for (int u = 0; u < 8; ++u)
                        vr[u] = *(const uint4*)&kv[ro[u] + 64 + j0];
                    #pragma unroll
                    for (int u = 0; u < 8; ++u) {
                        a[0] = fmaf(wgt[u], BF_LO(vr[u].x), a[0]);
                        a[1] = fmaf(wgt[u], BF_HI(vr[u].x), a[1]);
                        a[2] = fmaf(wgt[u], BF_LO(vr[u].y), a[2]);
                        a[3] = fmaf(wgt[u], BF_HI(vr[u].y), a[3]);
                        a[4] = fmaf(wgt[u], BF_LO(vr[u].z), a[4]);
                        a[5] = fmaf(wgt[u], BF_HI(vr[u].z), a[5]);
                        a[6] = fmaf(wgt[u], BF_LO(vr[u].w), a[6]);
                        a[7] = fmaf(wgt[u], BF_HI(vr[u].w), a[7]);
                    }
                }
            }
            for (; i < deg; ++i) {
                size_t ro = (size_t)esrc[start + i] * 128;
                uint4 kr = *(const uint4*)&kv[ro + j0];
                uint4 vr = *(const uint4*)&kv[ro + 64 + j0];
                float p = q0.x * BF_LO(kr.x) + q0.y * BF_HI(kr.x)
                        + q0.z * BF_LO(kr.y) + q0.w * BF_HI(kr.y)
                        + q1.x * BF_LO(kr.z) + q1.y * BF_HI(kr.z)
                        + q1.z * BF_LO(kr.w) + q1.w * BF_HI(kr.w);
                #pragma unroll
                for (int off = 1; off < 8; off <<= 1) p += __shfl_xor(p, off, 64);
                float wgt = __expf(p);
                z += wgt;
                a[0] = fmaf(wgt, BF_LO(vr.x), a[0]); a[1] = fmaf(wgt, BF_HI(vr.x), a[1]);
                a[2] = fmaf(wgt, BF_LO(vr.y), a[2]); a[3] = fmaf(wgt, BF_HI(vr.y), a[3]);
                a[4] = fmaf(wgt, BF_LO(vr.z), a[4]); a[5] = fmaf(wgt, BF_HI(vr.z), a[5]);
                a[6] = fmaf(wgt, BF_LO(vr.w), a[6]); a[7] = fmaf(wgt, BF_HI(vr.w), a[7]);
            }
            float o[8];
            if (deg > 0) {
                float inv = 1.0f / z;
                o[0] = fmaf(a[0], inv, s0.x); o[1] = fmaf(a[1], inv, s0.y);
                o[2] = fmaf(a[2], inv, s0.z); o[3] = fmaf(a[3], inv, s0.w);
                o[4] = fmaf(a[4], inv, s1.x); o[5] = fmaf(a[5], inv, s1.y);
                o[6] = fmaf(a[6], inv, s1.z); o[7] = fmaf(a[7], inv, s1.w);
            } else {
                o[0] = s0.x; o[1] = s0.y; o[2] = s0.z; o[3] = s0.w;
                o[4] = s1.x; o[5] = s1.y; o[6] = s1.z; o[7] = s1.w;
            }
            pk.x = pack2(o[0], o[1]); pk.y = pack2(o[2], o[3]);
            pk.z = pack2(o[4], o[5]); pk.w = pack2(o[6], o[7]);
        }
        *(uint4*)&sXb[local][j0] = pk;
    }
    __syncthreads();

    // ---- MFMA phase: [64 x 64] @ W2; 16 tiles, 2/wave ----
    int w = t >> 6;                 // 0..7
    int lane = t & 63;
    int l15 = lane & 15;
    int quad = lane >> 4;
    int rt = w >> 1;                // 0..3
    int ct0 = (w & 1) * 2;          // 0 or 2

    short8 a0 = *(const short8*)&sXb[rt * 16 + l15][quad * 8];
    short8 a1 = *(const short8*)&sXb[rt * 16 + l15][32 + quad * 8];

    #pragma unroll
    for (int tt = 0; tt < 2; ++tt) {
        int ct = ct0 + tt;
        int col = ct * 16 + l15;            // 0..63
        const unsigned short* wcol = &sWt[(size_t)col * 72];
        short8 bfr0 = *(const short8*)&wcol[quad * 8];
        short8 bfr1 = *(const short8*)&wcol[32 + quad * 8];
        f32x4 acc = {0.f, 0.f, 0.f, 0.f};
        acc = __builtin_amdgcn_mfma_f32_16x16x32_bf16(a0, bfr0, acc, 0, 0, 0);
        acc = __builtin_amdgcn_mfma_f32_16x16x32_bf16(a1, bfr1, acc, 0, 0, 0);
        #pragma unroll
        for (int rgi = 0; rgi < 4; ++rgi) {
            int row = base + rt * 16 + quad * 4 + rgi;
            if (row < n) {
                float dv = dinv[row];
                xs2[(size_t)row * 64 + col] = f2bf(acc[rgi] * dv);
            }
        }
    }
}

// ===================== GCN gather (bf16 rows, 8x8 grouped) =================
__global__ __launch_bounds__(256) void gcn_gather_kernel(const unsigned short* __restrict__ xs,
                                                         const float* __restrict__ dinv,
                                                         const int* __restrict__ rowptr,
                                                         const int* __restrict__ cnt,
                                                         const unsigned short* __restrict__ esrc,
                                                         const float* __restrict__ bias,
                                                         float* __restrict__ out,
                                                         int n, int relu) {
    int node = (blockIdx.x * blockDim.x + threadIdx.x) >> 6;
    if (node >= n) return;
    int lane = threadIdx.x & 63;
    int grp = lane >> 3;
    int sub = lane & 7;
    int j0 = sub * 8;

    int start = rowptr[node], deg = cnt[node];

    float a[8] = {0.f, 0.f, 0.f, 0.f, 0.f, 0.f, 0.f, 0.f};
    int i = grp;
    int sNext = (i < deg) ? esrc[start + i] : 0;
    for (; i < deg; i += 8) {
        int s = sNext;
        int in = i + 8;
        if (in < deg) sNext = esrc[start + in];
        uint4 r = *(const uint4*)&xs[(size_t)s * D + j0];
        a[0] += BF_LO(r.x); a[1] += BF_HI(r.x);
        a[2] += BF_LO(r.y); a[3] += BF_HI(r.y);
        a[4] += BF_LO(r.z); a[5] += BF_HI(r.z);
        a[6] += BF_LO(r.w); a[7] += BF_HI(r.w);
    }
    #pragma unroll
    for (int off = 8; off < 64; off <<= 1) {
        #pragma unroll
        for (int c = 0; c < 8; ++c) a[c] += __shfl_xor(a[c], off, 64);
    }

    if (grp == 0) {
        float dd = dinv[node];
        uint4 sr = *(const uint4*)&xs[(size_t)node * D + j0];
        a[0] += BF_LO(sr.x); a[1] += BF_HI(sr.x);
        a[2] += BF_LO(sr.y); a[3] += BF_HI(sr.y);
        a[4] += BF_LO(sr.z); a[5] += BF_HI(sr.z);
        a[6] += BF_LO(sr.w); a[7] += BF_HI(sr.w);
        float4 b0 = *(const float4*)&bias[j0];
        float4 b1 = *(const float4*)&bias[j0 + 4];
        float o[8];
        o[0] = fmaf(dd, a[0], b0.x); o[1] = fmaf(dd, a[1], b0.y);
        o[2] = fmaf(dd, a[2], b0.z); o[3] = fmaf(dd, a[3], b0.w);
        o[4] = fmaf(dd, a[4], b1.x); o[5] = fmaf(dd, a[5], b1.y);
        o[6] = fmaf(dd, a[6], b1.z); o[7] = fmaf(dd, a[7], b1.w);
        if (relu) {
            #pragma unroll
            for (int c = 0; c < 8; ++c) o[c] = fmaxf(o[c], 0.f);
        }
        *(float4*)&out[(size_t)node * D + j0] = make_float4(o[0], o[1], o[2], o[3]);
        *(float4*)&out[(size_t)node * D + j0 + 4] = make_float4(o[4], o[5], o[6], o[7]);
    }
}

// =============================== launch ====================================

extern "C" void kernel_launch(void* const* d_in, const int* in_sizes, int n_in,
                              void* d_out, int out_size, void* d_ws, size_t ws_size,
                              hipStream_t stream) {
    const float* x  = (const float*)d_in[0];
    const int*   ei = (const int*)d_in[1];
    const float* W1 = (const float*)d_in[2];
    const float* b1 = (const float*)d_in[3];
    const float* Wq = (const float*)d_in[4];
    const float* bq = (const float*)d_in[5];
    const float* Wk = (const float*)d_in[6];
    const float* bk = (const float*)d_in[7];
    const float* Wv = (const float*)d_in[8];
    const float* bv = (const float*)d_in[9];
    const float* Ws = (const float*)d_in[10];
    const float* bs = (const float*)d_in[11];
    const float* W2 = (const float*)d_in[12];
    const float* b2 = (const float*)d_in[13];
    float* out = (float*)d_out;

    const int n = in_sizes[0] / D;   // 50000  (< 65536 for 16-bit packing)
    const int e = in_sizes[1] / 2;   // 800000
    const int* src = ei;
    const int* dst = ei + e;
    const int n64 = n * D;
    const int nbkt = (n + (1 << BKT_SHIFT) - 1) >> BKT_SHIFT;   // 98

    char* w = (char*)d_ws;
    auto carve = [&](size_t bytes) {
        char* p = w;
        w += (bytes + 255) & ~(size_t)255;
        return p;
    };
    int* gcursor            = (int*)carve(128 * 4);
    unsigned int* staging   = (unsigned int*)carve((size_t)nbkt * CAP * 4);
    unsigned short* esrc    = (unsigned short*)carve((size_t)e * 2);
    int* cnt                = (int*)carve((size_t)n * 4);
    int* rowptr             = (int*)carve((size_t)n * 4);
    float* dinv             = (float*)carve((size_t)n * 4);
    float* bufQ             = (float*)carve((size_t)n64 * 4);   // q (pre-scaled)
    unsigned short* xs      = (unsigned short*)carve((size_t)n64 * 2);  // bf16 staging
    unsigned short* kv      = (unsigned short*)carve((size_t)n64 * 4);  // k|v bf16

    const int nb_binA = (e + CHUNK - 1) / CHUNK;   // 196
    const int nb_nw   = (n + 3) / 4;               // wave-per-node (final gather)
    const int nb_g    = (n + 63) / 64;             // 64 rows/block

    // ---- CSR build (2-phase binning) ----
    init_gcursor<<<1, 128, 0, stream>>>(gcursor);
    binA_kernel<<<nb_binA, 256, 0, stream>>>(src, dst, gcursor, staging, e, nbkt);
    binB_kernel<<<nbkt, 256, 0, stream>>>(gcursor, staging, esrc, cnt, rowptr, dinv, n, nbkt);

    // ---- layer 1 GEMM: xs = bf16((x@W1)*dinv) ----
    gemm64_bf16s<<<nb_g, 256, 0, stream>>>(x, W1, dinv, xs, n);

    // ---- fused: GCN1 gather -> x1 (LDS bf16) -> MFMA QKVS GEMM ----
    fusedA_kernel<<<nb_g, 512, 0, stream>>>(xs, dinv, rowptr, cnt, esrc, b1,
                                            Wq, bq, Wk, bk, Wv, bv, Ws, bs,
                                            bufQ, kv, out, n);   // skip -> out

    // ---- fused: attn gather -> x2 (LDS bf16) -> MFMA W2 GEMM -> xs ----
    fusedB_kernel<<<nb_g, 512, 0, stream>>>(bufQ, kv, out, dinv,
                                            rowptr, cnt, esrc, W2, xs, n);

    // ---- final GCN2 gather -> out ----
    gcn_gather_kernel<<<nb_nw, 256, 0, stream>>>(xs, dinv, rowptr, cnt, esrc,
                                                 b2, out, n, 0);
}